// Round 1
// baseline (2277.654 us; speedup 1.0000x reference)
//
#include <hip/hip_runtime.h>
#include <math.h>

// Problem constants (match setup_inputs)
constexpr int B = 2;
constexpr int S = 2048;
constexpr int DMODEL = 1024;
constexpr int H = 16;
constexpr int HD = 64;      // head dim
constexpr int ROT = 32;     // rotary dims (first 32 of each head)
constexpr int M_TOT = B * S;          // 4096 rows for projections
constexpr size_t MAT = (size_t)B * S * DMODEL;  // 4,194,304 elements

// ---------------------------------------------------------------------------
// GEMM: C = A(MxK) @ W(KxN) + bias, fp32, 64x64 tile, 256 threads, 4x4/thread
// blockIdx.z selects among up to 4 (W, bias, C) triples.
// ---------------------------------------------------------------------------
__global__ __launch_bounds__(256) void gemm_bias_kernel(
    const float* __restrict__ A,
    const float* W0, const float* W1, const float* W2, const float* W3,
    const float* b0, const float* b1, const float* b2, const float* b3,
    float* C0, float* C1, float* C2, float* C3,
    int M, int N, int K)
{
    const float* W;
    const float* bias;
    float* C;
    switch (blockIdx.z) {
        case 0: W = W0; bias = b0; C = C0; break;
        case 1: W = W1; bias = b1; C = C1; break;
        case 2: W = W2; bias = b2; C = C2; break;
        default: W = W3; bias = b3; C = C3; break;
    }

    constexpr int BM = 64, BN = 64, BK = 16;
    __shared__ float As[BM][BK + 1];
    __shared__ float Ws[BK][BN + 1];

    const int tid = threadIdx.x;
    const int row0 = blockIdx.y * BM;
    const int col0 = blockIdx.x * BN;
    const int tr = tid >> 4;   // 0..15
    const int tc = tid & 15;   // 0..15

    float acc[4][4] = {};

    for (int k0 = 0; k0 < K; k0 += BK) {
        // A tile: 64x16, each thread one float4
        {
            int r  = tid >> 2;
            int kq = (tid & 3) * 4;
            const float4 av = *reinterpret_cast<const float4*>(
                &A[(size_t)(row0 + r) * K + k0 + kq]);
            As[r][kq + 0] = av.x; As[r][kq + 1] = av.y;
            As[r][kq + 2] = av.z; As[r][kq + 3] = av.w;
        }
        // W tile: 16x64, each thread one float4
        {
            int kr = tid >> 4;
            int cq = (tid & 15) * 4;
            const float4 wv = *reinterpret_cast<const float4*>(
                &W[(size_t)(k0 + kr) * N + col0 + cq]);
            Ws[kr][cq + 0] = wv.x; Ws[kr][cq + 1] = wv.y;
            Ws[kr][cq + 2] = wv.z; Ws[kr][cq + 3] = wv.w;
        }
        __syncthreads();

        #pragma unroll
        for (int kk = 0; kk < BK; ++kk) {
            float a[4], bb[4];
            #pragma unroll
            for (int i = 0; i < 4; ++i) a[i]  = As[tr * 4 + i][kk];
            #pragma unroll
            for (int j = 0; j < 4; ++j) bb[j] = Ws[kk][tc * 4 + j];
            #pragma unroll
            for (int i = 0; i < 4; ++i)
                #pragma unroll
                for (int j = 0; j < 4; ++j)
                    acc[i][j] += a[i] * bb[j];
        }
        __syncthreads();
    }

    #pragma unroll
    for (int i = 0; i < 4; ++i) {
        int r = row0 + tr * 4 + i;
        #pragma unroll
        for (int j = 0; j < 4; ++j) {
            int c = col0 + tc * 4 + j;
            C[(size_t)r * N + c] = acc[i][j] + bias[c];
        }
    }
}

// ---------------------------------------------------------------------------
// xPos rotary on q (scale) and k (1/scale), in place.
// One block per (b,s); 256 threads = 16 heads x 16 freq-pairs.
// ---------------------------------------------------------------------------
__global__ __launch_bounds__(256) void rotary_kernel(float* __restrict__ q,
                                                     float* __restrict__ k)
{
    const int bs = blockIdx.x;            // 0..B*S-1
    const int s  = bs % S;
    const int h  = threadIdx.x >> 4;      // 0..15
    const int j  = threadIdx.x & 15;      // 0..15 freq pair

    const float inv_freq = powf(10000.0f, -(float)j / 16.0f); // theta^(-2j/ROT)
    const float freq = (float)s * inv_freq;
    const float c  = cosf(freq);
    const float sn = sinf(freq);

    const float base = (2.0f * j + 0.4f * ROT) / (1.4f * ROT);
    const float p    = ((float)s - (float)(S / 2)) / 512.0f;
    const float sc   = powf(base, p);

    const size_t off = (size_t)bs * DMODEL + h * HD + 2 * j;

    const float q0 = q[off], q1 = q[off + 1];
    q[off]     = (q0 * c - q1 * sn) * sc;
    q[off + 1] = (q1 * c + q0 * sn) * sc;

    const float isc = 1.0f / sc;
    const float k0 = k[off], k1 = k[off + 1];
    k[off]     = (k0 * c - k1 * sn) * isc;
    k[off + 1] = (k1 * c + k0 * sn) * isc;
}

// ---------------------------------------------------------------------------
// Retention: ret[b,h,s,:] = sum_j gamma^(s-j) (q_s . k_j) v_j  (causal),
// then row-scale by 1/sqrt(sum_j gamma^(s-j)).
// Block = (q-tile of 64 rows, h, b). 256 threads. Two-phase via LDS.
// ---------------------------------------------------------------------------
__global__ __launch_bounds__(256) void retention_kernel(
    const float* __restrict__ q, const float* __restrict__ k,
    const float* __restrict__ v, float* __restrict__ ret)
{
    __shared__ float qs[64][65];
    __shared__ float ks[64][65];
    __shared__ float vs[64][65];
    __shared__ float scs[64][65];

    const int st = blockIdx.x;   // q tile index (0..31)
    const int h  = blockIdx.y;
    const int b  = blockIdx.z;
    const int s0 = st * 64;
    const int tid = threadIdx.x;

    const float gamma = 1.0f - exp2f(-5.0f - (float)h);
    const float l2g   = log2f(gamma);

    const size_t base_off = (size_t)b * S * DMODEL + (size_t)h * HD;

    // load q tile (64 rows x 64 cols)
    {
        const int c = (tid & 15) * 4;
        #pragma unroll
        for (int pphase = 0; pphase < 4; ++pphase) {
            int r = pphase * 16 + (tid >> 4);
            const float4 qv = *reinterpret_cast<const float4*>(
                &q[base_off + (size_t)(s0 + r) * DMODEL + c]);
            qs[r][c + 0] = qv.x; qs[r][c + 1] = qv.y;
            qs[r][c + 2] = qv.z; qs[r][c + 3] = qv.w;
        }
    }

    const int sr  = (tid >> 4) * 4;   // phase-1 row base
    const int scq = (tid & 15) * 4;   // phase-1 col base
    const int r2  = tid >> 2;         // phase-2 row (0..63)
    const int dch = (tid & 3) * 16;   // phase-2 d base

    float acc[16] = {};

    for (int jt = 0; jt <= st; ++jt) {
        const int j0 = jt * 64;
        // load k, v tiles
        {
            const int c = (tid & 15) * 4;
            #pragma unroll
            for (int pphase = 0; pphase < 4; ++pphase) {
                int r = pphase * 16 + (tid >> 4);
                const float4 kv = *reinterpret_cast<const float4*>(
                    &k[base_off + (size_t)(j0 + r) * DMODEL + c]);
                ks[r][c + 0] = kv.x; ks[r][c + 1] = kv.y;
                ks[r][c + 2] = kv.z; ks[r][c + 3] = kv.w;
                const float4 vv = *reinterpret_cast<const float4*>(
                    &v[base_off + (size_t)(j0 + r) * DMODEL + c]);
                vs[r][c + 0] = vv.x; vs[r][c + 1] = vv.y;
                vs[r][c + 2] = vv.z; vs[r][c + 3] = vv.w;
            }
        }
        __syncthreads();

        // phase 1: 4x4 scores per thread
        {
            float dot[4][4] = {};
            for (int kk = 0; kk < 64; ++kk) {
                float a[4], bb[4];
                #pragma unroll
                for (int i = 0; i < 4; ++i) a[i]  = qs[sr + i][kk];
                #pragma unroll
                for (int j = 0; j < 4; ++j) bb[j] = ks[scq + j][kk];
                #pragma unroll
                for (int i = 0; i < 4; ++i)
                    #pragma unroll
                    for (int j = 0; j < 4; ++j)
                        dot[i][j] += a[i] * bb[j];
            }
            #pragma unroll
            for (int i = 0; i < 4; ++i) {
                #pragma unroll
                for (int j = 0; j < 4; ++j) {
                    int gi = s0 + sr + i, gj = j0 + scq + j;
                    float w = (gi >= gj) ? exp2f((float)(gi - gj) * l2g) : 0.0f;
                    scs[sr + i][scq + j] = dot[i][j] * w;
                }
            }
        }
        __syncthreads();

        // phase 2: acc += scores @ v   (16 d-values per thread)
        for (int jj = 0; jj < 64; ++jj) {
            const float sv = scs[r2][jj];
            #pragma unroll
            for (int dd = 0; dd < 16; ++dd)
                acc[dd] += sv * vs[jj][dch + dd];
        }
        __syncthreads();
    }

    // row normalizer: 1/sqrt((1 - gamma^(i+1)) / (1 - gamma))
    const int gi = s0 + r2;
    const float one_m_gpow = -expm1f((float)(gi + 1) * l2g * 0.6931471805599453f);
    const float invn = rsqrtf(one_m_gpow * exp2f(5.0f + (float)h));

    float* out = &ret[base_off + (size_t)gi * DMODEL + dch];
    #pragma unroll
    for (int dd = 0; dd < 16; ++dd)
        out[dd] = acc[dd] * invn;
}

// ---------------------------------------------------------------------------
// GroupNorm stats: mean & rstd over (S, HD) per (b,h). 32 blocks.
// ---------------------------------------------------------------------------
__global__ __launch_bounds__(256) void gn_stats_kernel(const float* __restrict__ ret,
                                                       float* __restrict__ stats)
{
    const int h = blockIdx.x & 15;
    const int b = blockIdx.x >> 4;
    float sum = 0.0f, sq = 0.0f;
    for (int idx = threadIdx.x; idx < S * HD; idx += 256) {
        int s  = idx >> 6;
        int dd = idx & 63;
        float val = ret[(size_t)(b * S + s) * DMODEL + h * HD + dd];
        sum += val;
        sq  += val * val;
    }
    #pragma unroll
    for (int o = 32; o > 0; o >>= 1) {
        sum += __shfl_down(sum, o, 64);
        sq  += __shfl_down(sq, o, 64);
    }
    __shared__ float rs[4], rq[4];
    const int wid = threadIdx.x >> 6, lane = threadIdx.x & 63;
    if (lane == 0) { rs[wid] = sum; rq[wid] = sq; }
    __syncthreads();
    if (threadIdx.x == 0) {
        float s1 = rs[0] + rs[1] + rs[2] + rs[3];
        float s2 = rq[0] + rq[1] + rq[2] + rq[3];
        const float inv_n = 1.0f / (float)(S * HD);
        float mean = s1 * inv_n;
        float var  = s2 * inv_n - mean * mean;
        stats[blockIdx.x * 2 + 0] = mean;
        stats[blockIdx.x * 2 + 1] = rsqrtf(var + 1e-5f);
    }
}

// ---------------------------------------------------------------------------
// Apply GN + gate: x2 = ((ret - mean) * rstd * gn_w[h] + gn_b[h]) * silu(g)
// In-place into g buffer. float4 grid-stride.
// ---------------------------------------------------------------------------
__device__ __forceinline__ float silu(float z) { return z / (1.0f + expf(-z)); }

__global__ __launch_bounds__(256) void gn_apply_kernel(
    const float* __restrict__ ret, float* __restrict__ g,
    const float* __restrict__ stats,
    const float* __restrict__ gnw, const float* __restrict__ gnb)
{
    const size_t n4 = MAT / 4;
    for (size_t p = (size_t)blockIdx.x * 256 + threadIdx.x; p < n4;
         p += (size_t)gridDim.x * 256) {
        const size_t el = p * 4;
        const int col = (int)(el & (DMODEL - 1));
        const int h   = col >> 6;
        const int b   = (int)(el / ((size_t)S * DMODEL));
        const int bh  = b * H + h;
        const float mean = stats[bh * 2 + 0];
        const float w    = stats[bh * 2 + 1] * gnw[h];
        const float bb   = gnb[h];
        const float4 r4 = reinterpret_cast<const float4*>(ret)[p];
        float4 g4 = reinterpret_cast<float4*>(g)[p];
        g4.x = ((r4.x - mean) * w + bb) * silu(g4.x);
        g4.y = ((r4.y - mean) * w + bb) * silu(g4.y);
        g4.z = ((r4.z - mean) * w + bb) * silu(g4.z);
        g4.w = ((r4.w - mean) * w + bb) * silu(g4.w);
        reinterpret_cast<float4*>(g)[p] = g4;
    }
}

// ---------------------------------------------------------------------------
extern "C" void kernel_launch(void* const* d_in, const int* in_sizes, int n_in,
                              void* d_out, int out_size, void* d_ws, size_t ws_size,
                              hipStream_t stream)
{
    const float* x   = (const float*)d_in[0];
    const float* Wq  = (const float*)d_in[1];
    const float* bq  = (const float*)d_in[2];
    const float* Wk  = (const float*)d_in[3];
    const float* bk  = (const float*)d_in[4];
    const float* Wv  = (const float*)d_in[5];
    const float* bv  = (const float*)d_in[6];
    const float* Wg  = (const float*)d_in[7];
    const float* bg  = (const float*)d_in[8];
    const float* Wo  = (const float*)d_in[9];
    const float* bo  = (const float*)d_in[10];
    const float* gnw = (const float*)d_in[11];
    const float* gnb = (const float*)d_in[12];
    float* out = (float*)d_out;

    float* ws = (float*)d_ws;
    float* q   = ws;
    float* k   = q + MAT;
    float* v   = k + MAT;
    float* g   = v + MAT;
    float* ret = g + MAT;
    float* stats = ret + MAT;  // 64 floats

    // 1) q,k,v,g projections (4 GEMMs in one launch via z)
    {
        dim3 grid(DMODEL / 64, M_TOT / 64, 4);
        gemm_bias_kernel<<<grid, 256, 0, stream>>>(
            x, Wq, Wk, Wv, Wg, bq, bk, bv, bg, q, k, v, g,
            M_TOT, DMODEL, DMODEL);
    }

    // 2) rotary xpos on q,k
    rotary_kernel<<<B * S, 256, 0, stream>>>(q, k);

    // 3) retention
    {
        dim3 grid(S / 64, H, B);
        retention_kernel<<<grid, 256, 0, stream>>>(q, k, v, ret);
    }

    // 4) group norm stats + apply with silu gate
    gn_stats_kernel<<<B * H, 256, 0, stream>>>(ret, stats);
    gn_apply_kernel<<<2048, 256, 0, stream>>>(ret, g, stats, gnw, gnb);

    // 5) output projection
    {
        dim3 grid(DMODEL / 64, M_TOT / 64, 1);
        gemm_bias_kernel<<<grid, 256, 0, stream>>>(
            g, Wo, Wo, Wo, Wo, bo, bo, bo, bo, out, out, out, out,
            M_TOT, DMODEL, DMODEL);
    }
}

// Round 2
// 207.294 us; speedup vs baseline: 10.9876x; 10.9876x over previous
//
#include <hip/hip_runtime.h>
#include <math.h>

constexpr int B = 2;
constexpr int S = 2048;
constexpr int DMODEL = 1024;
constexpr int H = 16;
constexpr int M_TOT = B * S;                     // 4096
constexpr size_t MAT = (size_t)B * S * DMODEL;   // 4,194,304 elements

typedef __attribute__((ext_vector_type(8))) __bf16 bf16x8;
typedef __attribute__((ext_vector_type(4))) float f32x4;

#define GLOAD16(g, l) __builtin_amdgcn_global_load_lds( \
    (const __attribute__((address_space(1))) void*)(g), \
    (__attribute__((address_space(3))) void*)(l), 16, 0, 0)

__device__ __forceinline__ float bf2f(__bf16 v) { return (float)v; }
__device__ __forceinline__ __bf16 f2bf(float v) { return (__bf16)v; }
__device__ __forceinline__ float silu(float z) { return z / (1.0f + expf(-z)); }

// ---------------------------------------------------------------------------
// Prep: x fp32 -> bf16 (8 elems / thread)
// ---------------------------------------------------------------------------
__global__ __launch_bounds__(256) void cvt_x_kernel(const float* __restrict__ x,
                                                    __bf16* __restrict__ xb)
{
    const size_t p = (size_t)blockIdx.x * 256 + threadIdx.x;  // group of 8
    const float4 a = reinterpret_cast<const float4*>(x)[2 * p];
    const float4 b = reinterpret_cast<const float4*>(x)[2 * p + 1];
    bf16x8 o;
    o[0] = f2bf(a.x); o[1] = f2bf(a.y); o[2] = f2bf(a.z); o[3] = f2bf(a.w);
    o[4] = f2bf(b.x); o[5] = f2bf(b.y); o[6] = f2bf(b.z); o[7] = f2bf(b.w);
    reinterpret_cast<bf16x8*>(xb)[p] = o;
}

// ---------------------------------------------------------------------------
// Prep: transpose + convert weights. z = 0..3 -> Wq,Wk,Wv,Wg into wqkvg_t
// (row n_global = z*1024 + n, col k). z = 4 -> Wo into wo_t.
// ---------------------------------------------------------------------------
__global__ __launch_bounds__(256) void transpose_w_kernel(
    const float* Wq, const float* Wk, const float* Wv, const float* Wg,
    const float* Wo, __bf16* __restrict__ wqkvg_t, __bf16* __restrict__ wo_t)
{
    __shared__ float tile[32][33];
    const int z = blockIdx.z;
    const float* W = (z == 0) ? Wq : (z == 1) ? Wk : (z == 2) ? Wv
                    : (z == 3) ? Wg : Wo;
    const int n0 = blockIdx.x * 32, k0 = blockIdx.y * 32;
    const int tx = threadIdx.x & 31, ty = threadIdx.x >> 5;  // 32 x 8

    #pragma unroll
    for (int i = 0; i < 32; i += 8)
        tile[ty + i][tx] = W[(size_t)(k0 + ty + i) * DMODEL + n0 + tx];
    __syncthreads();
    #pragma unroll
    for (int i = 0; i < 32; i += 8) {
        const int n = n0 + ty + i, kk = k0 + tx;
        const __bf16 val = f2bf(tile[tx][ty + i]);
        if (z < 4) wqkvg_t[((size_t)z * 1024 + n) * DMODEL + kk] = val;
        else       wo_t[(size_t)n * DMODEL + kk] = val;
    }
}

__global__ __launch_bounds__(256) void pack_bias_kernel(
    const float* bq, const float* bk, const float* bv, const float* bg,
    float* __restrict__ bqkvg)
{
    const int i = blockIdx.x * 256 + threadIdx.x;  // 0..4095
    const float* src = ((i >> 10) == 0) ? bq : ((i >> 10) == 1) ? bk
                      : ((i >> 10) == 2) ? bv : bg;
    bqkvg[i] = src[i & 1023];
}

// ---------------------------------------------------------------------------
// MFMA GEMM: C = A(MxK,bf16) @ Bt(NxK,bf16)^T + bias.
// 128x128 tile, BK=32, 256 threads (4 waves 2x2 of 64x64), global_load_lds.
// OUTMODE 0: bf16 out split into 4 buffers of width 1024 by col/1024.
// OUTMODE 1: f32 out, width N.
// ---------------------------------------------------------------------------
template <int OUTMODE>
__global__ __launch_bounds__(256) void gemm_mfma_kernel(
    const __bf16* __restrict__ A, const __bf16* __restrict__ Bt,
    const float* __restrict__ bias,
    __bf16* o0, __bf16* o1, __bf16* o2, __bf16* o3,
    float* fout, int M, int N, int K)
{
    __shared__ __bf16 a_lds[128 * 32];
    __shared__ __bf16 b_lds[128 * 32];

    const int t = threadIdx.x, wv = t >> 6, ln = t & 63;
    const int row0 = blockIdx.y * 128, col0 = blockIdx.x * 128;
    const int wr = (wv >> 1) * 64, wc = (wv & 1) * 64;
    const int lrow = ln & 15, lk8 = (ln >> 4) * 8;

    f32x4 acc[4][4] = {};

    for (int k0 = 0; k0 < K; k0 += 32) {
        __syncthreads();
        #pragma unroll
        for (int p = 0; p < 2; ++p) {
            const int ci = p * 256 + t;
            GLOAD16(A + (size_t)(row0 + (ci >> 2)) * K + k0 + (ci & 3) * 8,
                    (char*)a_lds + p * 4096 + wv * 1024);
            GLOAD16(Bt + (size_t)(col0 + (ci >> 2)) * K + k0 + (ci & 3) * 8,
                    (char*)b_lds + p * 4096 + wv * 1024);
        }
        __syncthreads();

        bf16x8 af[4], bf[4];
        #pragma unroll
        for (int mi = 0; mi < 4; ++mi)
            af[mi] = *reinterpret_cast<const bf16x8*>(
                &a_lds[(wr + mi * 16 + lrow) * 32 + lk8]);
        #pragma unroll
        for (int ni = 0; ni < 4; ++ni)
            bf[ni] = *reinterpret_cast<const bf16x8*>(
                &b_lds[(wc + ni * 16 + lrow) * 32 + lk8]);
        #pragma unroll
        for (int mi = 0; mi < 4; ++mi)
            #pragma unroll
            for (int ni = 0; ni < 4; ++ni)
                acc[mi][ni] = __builtin_amdgcn_mfma_f32_16x16x32_bf16(
                    af[mi], bf[ni], acc[mi][ni], 0, 0, 0);
    }

    if (OUTMODE == 0) {
        const int sel = col0 >> 10;
        __bf16* outp = (sel == 0) ? o0 : (sel == 1) ? o1 : (sel == 2) ? o2 : o3;
        #pragma unroll
        for (int mi = 0; mi < 4; ++mi) {
            #pragma unroll
            for (int ni = 0; ni < 4; ++ni) {
                const int cfull = col0 + wc + ni * 16 + (ln & 15);
                const float bs = bias[cfull];
                #pragma unroll
                for (int reg = 0; reg < 4; ++reg) {
                    const int r = row0 + wr + mi * 16 + (ln >> 4) * 4 + reg;
                    outp[(size_t)r * 1024 + (cfull & 1023)] =
                        f2bf(acc[mi][ni][reg] + bs);
                }
            }
        }
    } else {
        #pragma unroll
        for (int mi = 0; mi < 4; ++mi) {
            #pragma unroll
            for (int ni = 0; ni < 4; ++ni) {
                const int c = col0 + wc + ni * 16 + (ln & 15);
                const float bs = bias[c];
                #pragma unroll
                for (int reg = 0; reg < 4; ++reg) {
                    const int r = row0 + wr + mi * 16 + (ln >> 4) * 4 + reg;
                    fout[(size_t)r * N + c] = acc[mi][ni][reg] + bs;
                }
            }
        }
    }
}

// ---------------------------------------------------------------------------
// xPos rotary on bf16 q (scale) and k (1/scale), in place.
// ---------------------------------------------------------------------------
__global__ __launch_bounds__(256) void rotary_bf16_kernel(__bf16* __restrict__ q,
                                                          __bf16* __restrict__ k)
{
    const int bs = blockIdx.x;
    const int s  = bs & (S - 1);
    const int h  = threadIdx.x >> 4;
    const int j  = threadIdx.x & 15;

    const float inv_freq = powf(10000.0f, -(float)j / 16.0f);
    const float freq = (float)s * inv_freq;
    const float c  = cosf(freq);
    const float sn = sinf(freq);
    const float base = (2.0f * j + 0.4f * 32.0f) / (1.4f * 32.0f);
    const float p    = ((float)s - (float)(S / 2)) / 512.0f;
    const float sc   = powf(base, p);

    const size_t off = (size_t)bs * DMODEL + h * 64 + 2 * j;

    const float q0 = bf2f(q[off]), q1 = bf2f(q[off + 1]);
    q[off]     = f2bf((q0 * c - q1 * sn) * sc);
    q[off + 1] = f2bf((q1 * c + q0 * sn) * sc);

    const float isc = 1.0f / sc;
    const float k0 = bf2f(k[off]), k1 = bf2f(k[off + 1]);
    k[off]     = f2bf((k0 * c - k1 * sn) * isc);
    k[off + 1] = f2bf((k1 * c + k0 * sn) * isc);
}

// ---------------------------------------------------------------------------
// Retention via MFMA. Block = (q-tile of 64 rows, h, b), 256 thr = 4 waves.
// Wave w owns q rows w*16..w*16+15. Per k/v tile: QK^T (8 MFMA) -> decay
// weights in-register (multiplicative) -> P to LDS (bf16) -> PV (8 MFMA).
// V stored transposed in LDS with rotated-row layout (conflict-free).
// ---------------------------------------------------------------------------
__global__ __launch_bounds__(256) void retention_mfma_kernel(
    const __bf16* __restrict__ qg, const __bf16* __restrict__ kg,
    const __bf16* __restrict__ vg, float* __restrict__ ret)
{
    __shared__ __bf16 q_lds[64 * 72];
    __shared__ __bf16 k_lds[64 * 72];
    __shared__ __bf16 vt_lds[64 * 72];
    __shared__ __bf16 p_lds[64 * 72];

    const int st = blockIdx.x, h = blockIdx.y, b = blockIdx.z;
    const int s0 = st * 64;
    const int t = threadIdx.x, wv = t >> 6, ln = t & 63;
    const int lrow = ln & 15, lk8 = (ln >> 4) * 8;

    const float gamma = 1.0f - exp2f(-5.0f - (float)h);
    const float l2g   = log2f(gamma);
    const float gmn16 = exp2f(-16.0f * l2g);   // gamma^-16
    const size_t base = (size_t)b * S * DMODEL + h * 64;

    // stage q tile (64 x 64)
    #pragma unroll
    for (int p = 0; p < 2; ++p) {
        const int ci = p * 256 + t;
        const int r = ci >> 3, c8 = (ci & 7) * 8;
        *reinterpret_cast<bf16x8*>(&q_lds[r * 72 + c8]) =
            *reinterpret_cast<const bf16x8*>(
                &qg[base + (size_t)(s0 + r) * DMODEL + c8]);
    }

    f32x4 oacc[4] = {};

    for (int jt = 0; jt <= st; ++jt) {
        const int j0 = jt * 64;
        __syncthreads();
        // stage k (row-major) and v (transposed, rotated rows)
        #pragma unroll
        for (int p = 0; p < 2; ++p) {
            const int ci = p * 256 + t;
            const int r = ci >> 3, c8 = (ci & 7) * 8;
            *reinterpret_cast<bf16x8*>(&k_lds[r * 72 + c8]) =
                *reinterpret_cast<const bf16x8*>(
                    &kg[base + (size_t)(j0 + r) * DMODEL + c8]);
            const bf16x8 vvv = *reinterpret_cast<const bf16x8*>(
                &vg[base + (size_t)(j0 + r) * DMODEL + c8]);
            #pragma unroll
            for (int w = 0; w < 8; ++w) {
                const int d = c8 + w;
                const int col = (r + 8 * (d >> 3)) & 63;
                vt_lds[d * 72 + col] = vvv[w];
            }
        }
        __syncthreads();

        // QK^T -> sacc[ni] (16 rows x 64 j per wave)
        f32x4 sacc[4] = {};
        #pragma unroll
        for (int ks = 0; ks < 2; ++ks) {
            const bf16x8 aq = *reinterpret_cast<const bf16x8*>(
                &q_lds[(wv * 16 + lrow) * 72 + ks * 32 + lk8]);
            #pragma unroll
            for (int ni = 0; ni < 4; ++ni) {
                const bf16x8 bk = *reinterpret_cast<const bf16x8*>(
                    &k_lds[(ni * 16 + lrow) * 72 + ks * 32 + lk8]);
                sacc[ni] = __builtin_amdgcn_mfma_f32_16x16x32_bf16(
                    aq, bk, sacc[ni], 0, 0, 0);
            }
        }

        // decay weights (w = gamma^(i-j)) + causal mask, write P (bf16)
        const int di0 = (s0 + wv * 16 + (ln >> 4) * 4) - (j0 + (ln & 15));
        float w0 = exp2f((float)di0 * l2g);
        const bool diag = (jt == st);
        #pragma unroll
        for (int ni = 0; ni < 4; ++ni) {
            float wreg = w0;
            #pragma unroll
            for (int reg = 0; reg < 4; ++reg) {
                float wgt = wreg;
                if (diag && (di0 + reg - 16 * ni) < 0) wgt = 0.0f;
                const float pv = sacc[ni][reg] * wgt;
                p_lds[(wv * 16 + (ln >> 4) * 4 + reg) * 72 + ni * 16 + (ln & 15)]
                    = f2bf(pv);
                wreg *= gamma;
            }
            w0 *= gmn16;
        }

        // PV: oacc[nd] += P(16x64) @ V(64x64)
        #pragma unroll
        for (int ks = 0; ks < 2; ++ks) {
            const bf16x8 ap = *reinterpret_cast<const bf16x8*>(
                &p_lds[(wv * 16 + lrow) * 72 + ks * 32 + lk8]);
            #pragma unroll
            for (int nd = 0; nd < 4; ++nd) {
                const int d = nd * 16 + lrow;
                const int col = (ks * 32 + lk8 + 8 * (d >> 3)) & 63;
                const bf16x8 bv = *reinterpret_cast<const bf16x8*>(
                    &vt_lds[d * 72 + col]);
                oacc[nd] = __builtin_amdgcn_mfma_f32_16x16x32_bf16(
                    ap, bv, oacc[nd], 0, 0, 0);
            }
        }
    }

    // row normalizer 1/sqrt((1-gamma^(i+1))/(1-gamma)) and store f32
    const float sc5h = exp2f(5.0f + (float)h);
    #pragma unroll
    for (int reg = 0; reg < 4; ++reg) {
        const int i = s0 + wv * 16 + (ln >> 4) * 4 + reg;
        const float omg = 1.0f - exp2f((float)(i + 1) * l2g);
        const float invn = rsqrtf(omg * sc5h);
        #pragma unroll
        for (int nd = 0; nd < 4; ++nd)
            ret[base + (size_t)i * DMODEL + nd * 16 + (ln & 15)] =
                oacc[nd][reg] * invn;
    }
}

// ---------------------------------------------------------------------------
// GroupNorm stats, 2 stages.
// ---------------------------------------------------------------------------
__global__ __launch_bounds__(256) void gn_stats1_kernel(const float* __restrict__ ret,
                                                        float* __restrict__ part)
{
    const int sl = blockIdx.x;          // 0..15 slice of 128 rows
    const int bh = blockIdx.y;          // 0..31
    const int b = bh >> 4, h = bh & 15;
    const size_t rowbase = ((size_t)b * S + sl * 128) * DMODEL + h * 64;
    float sum = 0.0f, sq = 0.0f;
    #pragma unroll
    for (int it = 0; it < 8; ++it) {
        const int idx = it * 256 + threadIdx.x;  // float4 index
        const int row = idx >> 4;
        const int c4 = (idx & 15) * 4;
        const float4 v = *reinterpret_cast<const float4*>(
            &ret[rowbase + (size_t)row * DMODEL + c4]);
        sum += v.x + v.y + v.z + v.w;
        sq  += v.x * v.x + v.y * v.y + v.z * v.z + v.w * v.w;
    }
    #pragma unroll
    for (int o = 32; o > 0; o >>= 1) {
        sum += __shfl_down(sum, o, 64);
        sq  += __shfl_down(sq, o, 64);
    }
    __shared__ float rs[4], rq[4];
    const int wid = threadIdx.x >> 6, lane = threadIdx.x & 63;
    if (lane == 0) { rs[wid] = sum; rq[wid] = sq; }
    __syncthreads();
    if (threadIdx.x == 0) {
        part[(bh * 16 + sl) * 2 + 0] = rs[0] + rs[1] + rs[2] + rs[3];
        part[(bh * 16 + sl) * 2 + 1] = rq[0] + rq[1] + rq[2] + rq[3];
    }
}

__global__ __launch_bounds__(64) void gn_stats2_kernel(const float* __restrict__ part,
                                                       float* __restrict__ stats)
{
    const int bh = threadIdx.x;
    if (bh < 32) {
        float s = 0.0f, q2 = 0.0f;
        for (int i = 0; i < 16; ++i) {
            s  += part[(bh * 16 + i) * 2 + 0];
            q2 += part[(bh * 16 + i) * 2 + 1];
        }
        const float inv_n = 1.0f / (float)(S * 64);
        const float mean = s * inv_n;
        const float var  = q2 * inv_n - mean * mean;
        stats[bh * 2 + 0] = mean;
        stats[bh * 2 + 1] = rsqrtf(var + 1e-5f);
    }
}

// ---------------------------------------------------------------------------
// y = ((ret - mean) * rstd * gn_w[h] + gn_b[h]) * silu(g), bf16 out.
// ---------------------------------------------------------------------------
__global__ __launch_bounds__(256) void gn_apply_kernel(
    const float* __restrict__ ret, const __bf16* __restrict__ g,
    __bf16* __restrict__ y, const float* __restrict__ stats,
    const float* __restrict__ gnw, const float* __restrict__ gnb)
{
    const size_t p = (size_t)blockIdx.x * 256 + threadIdx.x;  // group of 8
    const size_t el = p * 8;
    const int col = (int)(el & (DMODEL - 1));
    const int h   = col >> 6;
    const int b   = (int)(el >> 21);              // S*DMODEL = 2^21
    const int bh  = b * H + h;
    const float mean = stats[bh * 2 + 0];
    const float w    = stats[bh * 2 + 1] * gnw[h];
    const float bb   = gnb[h];

    const float4 r0 = reinterpret_cast<const float4*>(ret)[2 * p];
    const float4 r1 = reinterpret_cast<const float4*>(ret)[2 * p + 1];
    const bf16x8 gv = reinterpret_cast<const bf16x8*>(g)[p];
    bf16x8 o;
    o[0] = f2bf(((r0.x - mean) * w + bb) * silu(bf2f(gv[0])));
    o[1] = f2bf(((r0.y - mean) * w + bb) * silu(bf2f(gv[1])));
    o[2] = f2bf(((r0.z - mean) * w + bb) * silu(bf2f(gv[2])));
    o[3] = f2bf(((r0.w - mean) * w + bb) * silu(bf2f(gv[3])));
    o[4] = f2bf(((r1.x - mean) * w + bb) * silu(bf2f(gv[4])));
    o[5] = f2bf(((r1.y - mean) * w + bb) * silu(bf2f(gv[5])));
    o[6] = f2bf(((r1.z - mean) * w + bb) * silu(bf2f(gv[6])));
    o[7] = f2bf(((r1.w - mean) * w + bb) * silu(bf2f(gv[7])));
    reinterpret_cast<bf16x8*>(y)[p] = o;
}

// ---------------------------------------------------------------------------
extern "C" void kernel_launch(void* const* d_in, const int* in_sizes, int n_in,
                              void* d_out, int out_size, void* d_ws, size_t ws_size,
                              hipStream_t stream)
{
    const float* x   = (const float*)d_in[0];
    const float* Wq  = (const float*)d_in[1];
    const float* bq  = (const float*)d_in[2];
    const float* Wk  = (const float*)d_in[3];
    const float* bk  = (const float*)d_in[4];
    const float* Wv  = (const float*)d_in[5];
    const float* bv  = (const float*)d_in[6];
    const float* Wg  = (const float*)d_in[7];
    const float* bg  = (const float*)d_in[8];
    const float* Wo  = (const float*)d_in[9];
    const float* bo  = (const float*)d_in[10];
    const float* gnw = (const float*)d_in[11];
    const float* gnb = (const float*)d_in[12];
    float* out = (float*)d_out;

    // workspace layout
    char* w = (char*)d_ws;
    __bf16* xb      = (__bf16*)w;               w += MAT * 2;            // 8.4MB
    __bf16* wqkvg_t = (__bf16*)w;               w += MAT * 2;            // 8.4MB
    __bf16* wo_t    = (__bf16*)w;               w += (size_t)DMODEL * DMODEL * 2;
    float*  bqkvg   = (float*)w;                w += 4096 * 4;
    __bf16* qb      = (__bf16*)w;               w += MAT * 2;
    __bf16* kb      = (__bf16*)w;               w += MAT * 2;
    __bf16* vb      = (__bf16*)w;               w += MAT * 2;
    __bf16* gb      = (__bf16*)w;               w += MAT * 2;
    float*  ret     = (float*)w;                w += MAT * 4;            // 16.8MB
    __bf16* yb      = (__bf16*)w;               w += MAT * 2;
    float*  part    = (float*)w;                w += 512 * 2 * 4;
    float*  stats   = (float*)w;                w += 64 * 4;

    // 1) prep
    cvt_x_kernel<<<2048, 256, 0, stream>>>(x, xb);
    {
        dim3 grid(32, 32, 5);
        transpose_w_kernel<<<grid, 256, 0, stream>>>(Wq, Wk, Wv, Wg, Wo,
                                                     wqkvg_t, wo_t);
    }
    pack_bias_kernel<<<16, 256, 0, stream>>>(bq, bk, bv, bg, bqkvg);

    // 2) fused QKVG projection GEMM (4096 x 4096 x 1024)
    {
        dim3 grid(32, 32);
        gemm_mfma_kernel<0><<<grid, 256, 0, stream>>>(
            xb, wqkvg_t, bqkvg, qb, kb, vb, gb, nullptr,
            M_TOT, 4096, DMODEL);
    }

    // 3) rotary xpos
    rotary_bf16_kernel<<<B * S, 256, 0, stream>>>(qb, kb);

    // 4) retention (MFMA)
    {
        dim3 grid(S / 64, H, B);
        retention_mfma_kernel<<<grid, 256, 0, stream>>>(qb, kb, vb, ret);
    }

    // 5) group norm + silu gate
    {
        dim3 grid(16, 32);
        gn_stats1_kernel<<<grid, 256, 0, stream>>>(ret, part);
    }
    gn_stats2_kernel<<<1, 64, 0, stream>>>(part, stats);
    gn_apply_kernel<<<2048, 256, 0, stream>>>(ret, gb, yb, stats, gnw, gnb);

    // 6) output GEMM (4096 x 1024 x 1024), f32 out
    {
        dim3 grid(8, 32);
        gemm_mfma_kernel<1><<<grid, 256, 0, stream>>>(
            yb, wo_t, bo, nullptr, nullptr, nullptr, nullptr, out,
            M_TOT, DMODEL, DMODEL);
    }
}